// Round 9
// baseline (178.839 us; speedup 1.0000x reference)
//
#include <hip/hip_runtime.h>

typedef float    f32x4  __attribute__((ext_vector_type(4)));
typedef float    f32x16 __attribute__((ext_vector_type(16)));
typedef __bf16   bf16x8 __attribute__((ext_vector_type(8)));
typedef __bf16   bf16x2 __attribute__((ext_vector_type(2)));
typedef unsigned uint2v __attribute__((ext_vector_type(2)));
typedef unsigned u32x4  __attribute__((ext_vector_type(4)));

union Frag { unsigned u[4]; bf16x8 b; };

static __device__ __forceinline__ unsigned pack2(float a, float b) {
    bf16x2 t;
    t[0] = (__bf16)a;
    t[1] = (__bf16)b;
    return __builtin_bit_cast(unsigned, t);
}

static __device__ __forceinline__ unsigned short f2bfu(float x) {
    __bf16 b = (__bf16)x;
    return __builtin_bit_cast(unsigned short, b);
}

// unpack packed-bf16 dword -> two f32 (lo element, hi element)
static __device__ __forceinline__ float bflo(unsigned u) { return __builtin_bit_cast(float, u << 16); }
static __device__ __forceinline__ float bfhi(unsigned u) { return __builtin_bit_cast(float, u & 0xffff0000u); }

static __device__ __forceinline__ uint2v pswap(unsigned a, unsigned b) {
#if __has_builtin(__builtin_amdgcn_permlane32_swap)
    return __builtin_amdgcn_permlane32_swap(a, b, false, false);
#else
    unsigned ax = (unsigned)__shfl_xor((int)a, 32);
    unsigned bx = (unsigned)__shfl_xor((int)b, 32);
    bool lo = (__lane_id() & 32) == 0;
    uint2v r;
    r[0] = lo ? a : bx;
    r[1] = lo ? ax : b;
    return r;
#endif
}

// ---------------------------------------------------------------------------
// Combined preprocess: blocks [0,320) weight scatter; blocks [320,...) x prep.
//  w1bf: [20][64][16] bf16 natural              (A-frag: lane 16B = 8 d)
//  w2f : [20][f][64][8] bf16, f=tg*4+kk, value = W2[m][32(f>>2)+(l&31)][16(f&3)+8(l>>5)+j]
//  w3b : [20][64] bf16 natural                  (broadcast A-frags for L3 MFMA)
//  b1p/b2p: [20][t][half][8] packed bf16 pairs in C-frag order:
//           dword q = pack(b[h0], b[h0+1]),  h0 = 32t + 4*half + (2q&3) + 8*(2q>>2)
//  xfbuf[((t32*2+half)*32+ln)*8 + j] = x[32*t32+ln][8*half+j]  (N*2 threads)
// ---------------------------------------------------------------------------
__global__ __launch_bounds__(256, 4) void prep_kernel(
    const float* __restrict__ W1, const float* __restrict__ W2,
    const float* __restrict__ b1, const float* __restrict__ b2,
    const float* __restrict__ W3,
    const float* __restrict__ Data,
    const float* __restrict__ Shift,
    const float* __restrict__ Scaling,
    unsigned short* __restrict__ w1bf, unsigned short* __restrict__ w2f,
    unsigned short* __restrict__ w3b,
    unsigned* __restrict__ b1p, unsigned* __restrict__ b2p,
    unsigned short* __restrict__ xfbuf)
{
    if (blockIdx.x < 320) {
        const int t = blockIdx.x * 256 + threadIdx.x;
        if (t < 20480) w1bf[t] = f2bfu(W1[t]);
        if (t < 81920) {
            const int j = t & 7, l = (t >> 3) & 63, f = (t >> 9) & 7, m = t >> 12;
            const int g = 32 * (f >> 2) + (l & 31);
            const int h = 16 * (f & 3) + 8 * (l >> 5) + j;
            w2f[t] = f2bfu(W2[(m * 64 + g) * 64 + h]);
        }
        if (t < 1280) w3b[t] = f2bfu(W3[t]);
        if (t < 640) {
            const int q = t & 7, hf = (t >> 3) & 1, tt = (t >> 4) & 1, m = t >> 5;
            const int h0 = 32 * tt + 4 * hf + ((2 * q) & 3) + 8 * ((2 * q) >> 2);
            b1p[t] = pack2(b1[m * 64 + h0], b1[m * 64 + h0 + 1]);
            b2p[t] = pack2(b2[m * 64 + h0], b2[m * 64 + h0 + 1]);
        }
    } else {
        const int g    = (blockIdx.x - 320) * 256 + threadIdx.x;
        const int ln   = g & 31, half = (g >> 5) & 1, t32 = g >> 6;
        const float* dp = Data + (size_t)(t32 * 32 + ln) * 16 + 8 * half;
        f32x4 v0 = *(const f32x4*)dp;
        f32x4 v1 = *(const f32x4*)(dp + 4);
        float xv[8];
        #pragma unroll
        for (int j = 0; j < 4; ++j) {
            xv[j]     = (v0[j] - Shift[8 * half + j])     / Scaling[8 * half + j];
            xv[4 + j] = (v1[j] - Shift[8 * half + 4 + j]) / Scaling[8 * half + 4 + j];
        }
        u32x4 o;
        #pragma unroll
        for (int c = 0; c < 4; ++c) o[c] = pack2(xv[2 * c], xv[2 * c + 1]);
        *(u32x4*)(xfbuf + (size_t)g * 8) = o;
    }
}

// ---------------------------------------------------------------------------
// MLP, weight-stationary, E=4 per iteration. R8 post-mortem: compiler pins
// this code at a 100-VGPR serialized schedule regardless of source-level ILP
// (R7 bias regs and R8 chains both rejected). So stop granting 256 VGPR/wave:
// __launch_bounds__(256,4) caps at 128 >= the compiler's natural 100 (no
// spill) and doubles residency to 4 waves/SIMD -- TLP fills the VALU/MFMA
// issue slots that single-wave dependency stalls leave empty.
// Spill tripwire: WRITE_SIZE must stay ~10.2 MB.
// ---------------------------------------------------------------------------
__global__ __launch_bounds__(256, 4) void mlp_kernel(
    const unsigned short* __restrict__ w1bf,
    const unsigned short* __restrict__ w2f,
    const unsigned short* __restrict__ w3b,
    const unsigned* __restrict__ b1p,
    const unsigned* __restrict__ b2p,
    const float* __restrict__ b3,
    const unsigned short* __restrict__ xfbuf,
    float* __restrict__ out, int N)
{
    const int tid  = threadIdx.x;
    const int wave = tid >> 6;
    const int lane = tid & 63;
    const int ln   = lane & 31;
    const int half = lane >> 5;
    const int mg   = blockIdx.x % 5;
    const int eb   = blockIdx.x / 5;          // 0..511, 256 events each
    const int m    = mg * 4 + wave;

    // ---- load-once, register-resident ----
    bf16x8 a1[2];
    #pragma unroll
    for (int t = 0; t < 2; ++t)
        a1[t] = *(const bf16x8*)(w1bf + (size_t)(m * 64 + 32 * t + ln) * 16 + 8 * half);
    bf16x8 a2[8];
    #pragma unroll
    for (int f = 0; f < 8; ++f)
        a2[f] = *(const bf16x8*)(w2f + (size_t)((m * 8 + f) * 64 + lane) * 8);
    bf16x8 a3[4];   // w3 broadcast slices: every A row = w3[16s + 8half + j]
    #pragma unroll
    for (int s = 0; s < 4; ++s)
        a3[s] = *(const bf16x8*)(w3b + m * 64 + s * 16 + 8 * half);
    const float b3v = b3[m];

    // packed biases (16 dwords persistent; unpack per use -- VALU has slack)
    u32x4 b1r[2][2], b2r[2][2];
    #pragma unroll
    for (int t = 0; t < 2; ++t) {
        const unsigned* p1 = b1p + ((m * 2 + t) * 2 + half) * 8;
        b1r[t][0] = *(const u32x4*)p1;
        b1r[t][1] = *(const u32x4*)(p1 + 4);
        const unsigned* p2 = b2p + ((m * 2 + t) * 2 + half) * 8;
        b2r[t][0] = *(const u32x4*)p2;
        b2r[t][1] = *(const u32x4*)(p2 + 4);
    }

    // all 8 x-fragments for this wave's 256 events (32 regs)
    bf16x8 xf[8];
    #pragma unroll
    for (int f = 0; f < 8; ++f)
        xf[f] = *(const bf16x8*)(xfbuf + ((size_t)(eb * 8 + f) * 2 + half) * 256 + ln * 8);

    #pragma unroll
    for (int it = 0; it < 2; ++it) {
        float res[4];
        #pragma unroll
        for (int e = 0; e < 4; ++e) {
            const bf16x8 xfe = xf[it * 4 + e];
            // ---- L1 ----
            unsigned bfr[4][4];
            #pragma unroll
            for (int t = 0; t < 2; ++t) {
                f32x16 acc;
                #pragma unroll
                for (int hq = 0; hq < 2; ++hq)
                    #pragma unroll
                    for (int q4 = 0; q4 < 4; ++q4) {
                        const unsigned u = b1r[t][hq][q4];
                        acc[8 * hq + 2 * q4]     = bflo(u);
                        acc[8 * hq + 2 * q4 + 1] = bfhi(u);
                    }
                acc = __builtin_amdgcn_mfma_f32_32x32x16_bf16(a1[t], xfe, acc, 0, 0, 0);
                unsigned p[8];
                #pragma unroll
                for (int q = 0; q < 8; ++q)
                    p[q] = pack2(fmaxf(acc[2 * q], 0.f), fmaxf(acc[2 * q + 1], 0.f));
                uint2v r0 = pswap(p[0], p[2]);
                uint2v r1 = pswap(p[1], p[3]);
                uint2v r2 = pswap(p[4], p[6]);
                uint2v r3 = pswap(p[5], p[7]);
                bfr[2 * t    ][0] = r0[0]; bfr[2 * t    ][1] = r1[0];
                bfr[2 * t    ][2] = r0[1]; bfr[2 * t    ][3] = r1[1];
                bfr[2 * t + 1][0] = r2[0]; bfr[2 * t + 1][1] = r3[0];
                bfr[2 * t + 1][2] = r2[1]; bfr[2 * t + 1][3] = r3[1];
            }
            // ---- L2 ----
            unsigned pb[4][4];
            f32x16 acc;
            #pragma unroll
            for (int tg = 0; tg < 2; ++tg) {
                f32x16 ci;
                #pragma unroll
                for (int hq = 0; hq < 2; ++hq)
                    #pragma unroll
                    for (int q4 = 0; q4 < 4; ++q4) {
                        const unsigned u = b2r[tg][hq][q4];
                        ci[8 * hq + 2 * q4]     = bflo(u);
                        ci[8 * hq + 2 * q4 + 1] = bfhi(u);
                    }
                #pragma unroll
                for (int kk = 0; kk < 4; ++kk) {
                    Frag fb;
                    #pragma unroll
                    for (int c = 0; c < 4; ++c) fb.u[c] = bfr[kk][c];
                    acc = __builtin_amdgcn_mfma_f32_32x32x16_bf16(
                        a2[tg * 4 + kk], fb.b, kk == 0 ? ci : acc, 0, 0, 0);
                }
                unsigned p[8];
                #pragma unroll
                for (int q = 0; q < 8; ++q)
                    p[q] = pack2(fmaxf(acc[2 * q], 0.f), fmaxf(acc[2 * q + 1], 0.f));
                uint2v r0 = pswap(p[0], p[2]);
                uint2v r1 = pswap(p[1], p[3]);
                uint2v r2 = pswap(p[4], p[6]);
                uint2v r3 = pswap(p[5], p[7]);
                pb[2 * tg    ][0] = r0[0]; pb[2 * tg    ][1] = r1[0];
                pb[2 * tg    ][2] = r0[1]; pb[2 * tg    ][3] = r1[1];
                pb[2 * tg + 1][0] = r2[0]; pb[2 * tg + 1][1] = r3[0];
                pb[2 * tg + 1][2] = r2[1]; pb[2 * tg + 1][3] = r3[1];
            }
            // ---- L3: broadcast-A MFMA chain; only row-0 reg is consumed ----
            acc[0] = b3v;
            #pragma unroll
            for (int s = 0; s < 4; ++s) {
                Frag fb;
                #pragma unroll
                for (int c = 0; c < 4; ++c) fb.u[c] = pb[s][c];
                acc = __builtin_amdgcn_mfma_f32_32x32x16_bf16(a3[s], fb.b, acc, 0, 0, 0);
            }
            res[e] = acc[0];
        }
        // two coalesced 64-wide stores per iteration
        const size_t base = (size_t)m * N + eb * 256 + it * 128;
        out[base + lane]      = half ? res[1] : res[0];
        out[base + 64 + lane] = half ? res[3] : res[2];
    }
}

// ---------------------------------------------------------------------------
// rho epilogue: block = 64 events, k = lane.
// ---------------------------------------------------------------------------
__global__ __launch_bounds__(256, 8) void rho_kernel(
    const float* __restrict__ Parameters,
    const float* __restrict__ PScal,
    const float* __restrict__ out,
    float* __restrict__ rho, int N)
{
    __shared__ float o[64][22];
    const int tid = threadIdx.x;
    const int nb  = blockIdx.x * 64;

    for (int i = tid; i < 20 * 64; i += 256) {
        const int mm = i >> 6, ev = i & 63;
        o[ev][mm] = out[(size_t)mm * N + nb + ev];
    }

    const int lane = tid & 63;
    const int wave = tid >> 6;
    const float pk1 = Parameters[lane * 5 + 0] / PScal[0];
    const float pk2 = Parameters[lane * 5 + 1] / PScal[1];
    const float pk3 = Parameters[lane * 5 + 2] / PScal[2];
    const float pk4 = Parameters[lane * 5 + 3] / PScal[3];
    const float pk5 = Parameters[lane * 5 + 4] / PScal[4];

    __syncthreads();

    #pragma unroll 4
    for (int i = 0; i < 16; ++i) {
        const int ev = wave * 16 + i;
        const float* r = &o[ev][0];
        float m0 = 1.0f + r[0] * pk1 + r[1] * pk2 + r[2] * pk3 + r[3] * pk4 + r[4] * pk5;
        float m1 = r[5] * pk1 + r[6] * pk2 + r[7] * pk3 + r[8] * pk4 + r[9] * pk5;
        float m2 = r[10] * pk2 + r[11] * pk3 + r[12] * pk4 + r[13] * pk5;
        float m3 = r[14] * pk3 + r[15] * pk4 + r[16] * pk5;
        float m4 = r[17] * pk4 + r[18] * pk5;
        float m5 = r[19] * pk5;
        float v = m0 * m0 + m1 * m1 + m2 * m2 + m3 * m3 + m4 * m4 + m5 * m5;
        rho[(size_t)(nb + ev) * 64 + lane] = v;
    }
}

extern "C" void kernel_launch(void* const* d_in, const int* in_sizes, int n_in,
                              void* d_out, int out_size, void* d_ws, size_t ws_size,
                              hipStream_t stream)
{
    const float* Data   = (const float*)d_in[0];
    const float* Params = (const float*)d_in[1];
    const float* Shift  = (const float*)d_in[2];
    const float* Scal   = (const float*)d_in[3];
    const float* PScal  = (const float*)d_in[4];
    const float* W1     = (const float*)d_in[5];
    const float* b1     = (const float*)d_in[6];
    const float* W2     = (const float*)d_in[7];
    const float* b2     = (const float*)d_in[8];
    const float* W3     = (const float*)d_in[9];
    const float* b3     = (const float*)d_in[10];
    float* rho = (float*)d_out;
    const int N = in_sizes[0] / 16;   // 131072

    char* ws = (char*)d_ws;
    unsigned short* w1bf = (unsigned short*)(ws);             //      0 .. 40960
    unsigned short* w2f  = (unsigned short*)(ws + 40960);     //  40960 .. 204800
    unsigned short* w3b  = (unsigned short*)(ws + 204800);    // 204800 .. 207360
    unsigned*       b1p  = (unsigned*)(ws + 207360);          // 207360 .. 209920
    unsigned*       b2p  = (unsigned*)(ws + 209920);          // 209920 .. 212480
    unsigned short* xfb  = (unsigned short*)(ws + 262144);    // 4 MB
    float*          out  = (float*)(ws + 262144 + 4194304);   // 10.5 MB ([20][N])

    prep_kernel<<<320 + N / 128, 256, 0, stream>>>(W1, W2, b1, b2, W3,
                                                   Data, Shift, Scal,
                                                   w1bf, w2f, w3b, b1p, b2p, xfb);
    mlp_kernel<<<5 * (N / 256), 256, 0, stream>>>(w1bf, w2f, w3b, b1p, b2p, b3, xfb, out, N);
    rho_kernel<<<N / 64, 256, 0, stream>>>(Params, PScal, out, rho, N);
}

// Round 10
// 110.410 us; speedup vs baseline: 1.6198x; 1.6198x over previous
//
#include <hip/hip_runtime.h>

typedef float    f32x4  __attribute__((ext_vector_type(4)));
typedef float    f32x16 __attribute__((ext_vector_type(16)));
typedef __bf16   bf16x8 __attribute__((ext_vector_type(8)));
typedef __bf16   bf16x2 __attribute__((ext_vector_type(2)));
typedef unsigned uint2v __attribute__((ext_vector_type(2)));
typedef unsigned u32x4  __attribute__((ext_vector_type(4)));

union Frag { unsigned u[4]; bf16x8 b; };

static __device__ __forceinline__ unsigned pack2(float a, float b) {
    bf16x2 t;
    t[0] = (__bf16)a;
    t[1] = (__bf16)b;
    return __builtin_bit_cast(unsigned, t);
}

// packed relu on 2xbf16: bf16 bit patterns reinterpret as f16 with monotone
// ordering (NaN/inf f16 patterns require bf16 exp >= 0xF8 <=> |x| >= 2^121,
// unreachable here), so v_pk_max_f16 with +0 is exact bf16 relu.
// 1 cvt_pk + 1 pk_max = 2 instr/dword vs 2 fmax + 1 cvt_pk = 3.
static __device__ __forceinline__ unsigned relupk(float a, float b, unsigned zero) {
    unsigned x = pack2(a, b), r;
    asm("v_pk_max_f16 %0, %1, %2" : "=v"(r) : "v"(x), "v"(zero));
    return r;
}

static __device__ __forceinline__ unsigned short f2bfu(float x) {
    __bf16 b = (__bf16)x;
    return __builtin_bit_cast(unsigned short, b);
}

// unpack packed-bf16 dword -> two f32 (lo element, hi element)
static __device__ __forceinline__ float bflo(unsigned u) { return __builtin_bit_cast(float, u << 16); }
static __device__ __forceinline__ float bfhi(unsigned u) { return __builtin_bit_cast(float, u & 0xffff0000u); }

static __device__ __forceinline__ uint2v pswap(unsigned a, unsigned b) {
#if __has_builtin(__builtin_amdgcn_permlane32_swap)
    return __builtin_amdgcn_permlane32_swap(a, b, false, false);
#else
    unsigned ax = (unsigned)__shfl_xor((int)a, 32);
    unsigned bx = (unsigned)__shfl_xor((int)b, 32);
    bool lo = (__lane_id() & 32) == 0;
    uint2v r;
    r[0] = lo ? a : bx;
    r[1] = lo ? ax : b;
    return r;
#endif
}

// ---------------------------------------------------------------------------
// Combined preprocess: blocks [0,320) weight scatter; blocks [320,...) x prep.
//  w1bf: [20][64][16] bf16 natural              (A-frag: lane 16B = 8 d)
//  w2f : [20][f][64][8] bf16, f=tg*4+kk, value = W2[m][32(f>>2)+(l&31)][16(f&3)+8(l>>5)+j]
//  w3b : [20][64] bf16 natural                  (broadcast A-frags for L3 MFMA)
//  b1p/b2p: [20][t][half][8] packed bf16 pairs in C-frag order:
//           dword q = pack(b[h0], b[h0+1]),  h0 = 32t + 4*half + (2q&3) + 8*(2q>>2)
//  xfbuf[((t32*2+half)*32+ln)*8 + j] = x[32*t32+ln][8*half+j]  (N*2 threads)
// ---------------------------------------------------------------------------
__global__ __launch_bounds__(256, 4) void prep_kernel(
    const float* __restrict__ W1, const float* __restrict__ W2,
    const float* __restrict__ b1, const float* __restrict__ b2,
    const float* __restrict__ W3,
    const float* __restrict__ Data,
    const float* __restrict__ Shift,
    const float* __restrict__ Scaling,
    unsigned short* __restrict__ w1bf, unsigned short* __restrict__ w2f,
    unsigned short* __restrict__ w3b,
    unsigned* __restrict__ b1p, unsigned* __restrict__ b2p,
    unsigned short* __restrict__ xfbuf)
{
    if (blockIdx.x < 320) {
        const int t = blockIdx.x * 256 + threadIdx.x;
        if (t < 20480) w1bf[t] = f2bfu(W1[t]);
        if (t < 81920) {
            const int j = t & 7, l = (t >> 3) & 63, f = (t >> 9) & 7, m = t >> 12;
            const int g = 32 * (f >> 2) + (l & 31);
            const int h = 16 * (f & 3) + 8 * (l >> 5) + j;
            w2f[t] = f2bfu(W2[(m * 64 + g) * 64 + h]);
        }
        if (t < 1280) w3b[t] = f2bfu(W3[t]);
        if (t < 640) {
            const int q = t & 7, hf = (t >> 3) & 1, tt = (t >> 4) & 1, m = t >> 5;
            const int h0 = 32 * tt + 4 * hf + ((2 * q) & 3) + 8 * ((2 * q) >> 2);
            b1p[t] = pack2(b1[m * 64 + h0], b1[m * 64 + h0 + 1]);
            b2p[t] = pack2(b2[m * 64 + h0], b2[m * 64 + h0 + 1]);
        }
    } else {
        const int g    = (blockIdx.x - 320) * 256 + threadIdx.x;
        const int ln   = g & 31, half = (g >> 5) & 1, t32 = g >> 6;
        const float* dp = Data + (size_t)(t32 * 32 + ln) * 16 + 8 * half;
        f32x4 v0 = *(const f32x4*)dp;
        f32x4 v1 = *(const f32x4*)(dp + 4);
        float xv[8];
        #pragma unroll
        for (int j = 0; j < 4; ++j) {
            xv[j]     = (v0[j] - Shift[8 * half + j])     / Scaling[8 * half + j];
            xv[4 + j] = (v1[j] - Shift[8 * half + 4 + j]) / Scaling[8 * half + 4 + j];
        }
        u32x4 o;
        #pragma unroll
        for (int c = 0; c < 4; ++c) o[c] = pack2(xv[2 * c], xv[2 * c + 1]);
        *(u32x4*)(xfbuf + (size_t)g * 8) = o;
    }
}

// ---------------------------------------------------------------------------
// MLP, weight-stationary, E=4 per iteration.
// R9 post-mortem: gfx950 unified VGPR/AGPR file -- kernel needs ~100 arch +
// ~50 acc = ~155 TOTAL regs. 4 waves/SIMD (128 budget) forces spills (R9:
// 614 MB scratch); 2 waves (512) wastes the file. __launch_bounds__(256,3)
// = 170 budget >= 155: 3 waves/SIMD, +50% TLP to cover dependency stalls
// (R8: busy-sum 66k cyc vs 120k wall). Spill tripwire: WRITE_SIZE ~10.2 MB.
// ---------------------------------------------------------------------------
__global__ __launch_bounds__(256, 3) void mlp_kernel(
    const unsigned short* __restrict__ w1bf,
    const unsigned short* __restrict__ w2f,
    const unsigned short* __restrict__ w3b,
    const unsigned* __restrict__ b1p,
    const unsigned* __restrict__ b2p,
    const float* __restrict__ b3,
    const unsigned short* __restrict__ xfbuf,
    float* __restrict__ out, int N)
{
    const int tid  = threadIdx.x;
    const int wave = tid >> 6;
    const int lane = tid & 63;
    const int ln   = lane & 31;
    const int half = lane >> 5;
    const int mg   = blockIdx.x % 5;
    const int eb   = blockIdx.x / 5;          // 0..511, 256 events each
    const int m    = mg * 4 + wave;

    unsigned zero = 0;
    asm volatile("" : "+v"(zero));   // pin 0 in a VGPR for v_pk_max_f16

    // ---- load-once, register-resident ----
    bf16x8 a1[2];
    #pragma unroll
    for (int t = 0; t < 2; ++t)
        a1[t] = *(const bf16x8*)(w1bf + (size_t)(m * 64 + 32 * t + ln) * 16 + 8 * half);
    bf16x8 a2[8];
    #pragma unroll
    for (int f = 0; f < 8; ++f)
        a2[f] = *(const bf16x8*)(w2f + (size_t)((m * 8 + f) * 64 + lane) * 8);
    bf16x8 a3[4];   // w3 broadcast slices: every A row = w3[16s + 8half + j]
    #pragma unroll
    for (int s = 0; s < 4; ++s)
        a3[s] = *(const bf16x8*)(w3b + m * 64 + s * 16 + 8 * half);
    const float b3v = b3[m];

    // packed biases (16 dwords persistent; unpack per use -- VALU has slack)
    u32x4 b1r[2][2], b2r[2][2];
    #pragma unroll
    for (int t = 0; t < 2; ++t) {
        const unsigned* p1 = b1p + ((m * 2 + t) * 2 + half) * 8;
        b1r[t][0] = *(const u32x4*)p1;
        b1r[t][1] = *(const u32x4*)(p1 + 4);
        const unsigned* p2 = b2p + ((m * 2 + t) * 2 + half) * 8;
        b2r[t][0] = *(const u32x4*)p2;
        b2r[t][1] = *(const u32x4*)(p2 + 4);
    }

    // all 8 x-fragments for this wave's 256 events (32 regs)
    bf16x8 xf[8];
    #pragma unroll
    for (int f = 0; f < 8; ++f)
        xf[f] = *(const bf16x8*)(xfbuf + ((size_t)(eb * 8 + f) * 2 + half) * 256 + ln * 8);

    #pragma unroll
    for (int it = 0; it < 2; ++it) {
        float res[4];
        #pragma unroll
        for (int e = 0; e < 4; ++e) {
            const bf16x8 xfe = xf[it * 4 + e];
            // ---- L1 ----
            unsigned bfr[4][4];
            #pragma unroll
            for (int t = 0; t < 2; ++t) {
                f32x16 acc;
                #pragma unroll
                for (int hq = 0; hq < 2; ++hq)
                    #pragma unroll
                    for (int q4 = 0; q4 < 4; ++q4) {
                        const unsigned u = b1r[t][hq][q4];
                        acc[8 * hq + 2 * q4]     = bflo(u);
                        acc[8 * hq + 2 * q4 + 1] = bfhi(u);
                    }
                acc = __builtin_amdgcn_mfma_f32_32x32x16_bf16(a1[t], xfe, acc, 0, 0, 0);
                unsigned p[8];
                #pragma unroll
                for (int q = 0; q < 8; ++q)
                    p[q] = relupk(acc[2 * q], acc[2 * q + 1], zero);
                uint2v r0 = pswap(p[0], p[2]);
                uint2v r1 = pswap(p[1], p[3]);
                uint2v r2 = pswap(p[4], p[6]);
                uint2v r3 = pswap(p[5], p[7]);
                bfr[2 * t    ][0] = r0[0]; bfr[2 * t    ][1] = r1[0];
                bfr[2 * t    ][2] = r0[1]; bfr[2 * t    ][3] = r1[1];
                bfr[2 * t + 1][0] = r2[0]; bfr[2 * t + 1][1] = r3[0];
                bfr[2 * t + 1][2] = r2[1]; bfr[2 * t + 1][3] = r3[1];
            }
            // ---- L2 ----
            unsigned pb[4][4];
            f32x16 acc;
            #pragma unroll
            for (int tg = 0; tg < 2; ++tg) {
                f32x16 ci;
                #pragma unroll
                for (int hq = 0; hq < 2; ++hq)
                    #pragma unroll
                    for (int q4 = 0; q4 < 4; ++q4) {
                        const unsigned u = b2r[tg][hq][q4];
                        ci[8 * hq + 2 * q4]     = bflo(u);
                        ci[8 * hq + 2 * q4 + 1] = bfhi(u);
                    }
                #pragma unroll
                for (int kk = 0; kk < 4; ++kk) {
                    Frag fb;
                    #pragma unroll
                    for (int c = 0; c < 4; ++c) fb.u[c] = bfr[kk][c];
                    acc = __builtin_amdgcn_mfma_f32_32x32x16_bf16(
                        a2[tg * 4 + kk], fb.b, kk == 0 ? ci : acc, 0, 0, 0);
                }
                unsigned p[8];
                #pragma unroll
                for (int q = 0; q < 8; ++q)
                    p[q] = relupk(acc[2 * q], acc[2 * q + 1], zero);
                uint2v r0 = pswap(p[0], p[2]);
                uint2v r1 = pswap(p[1], p[3]);
                uint2v r2 = pswap(p[4], p[6]);
                uint2v r3 = pswap(p[5], p[7]);
                pb[2 * tg    ][0] = r0[0]; pb[2 * tg    ][1] = r1[0];
                pb[2 * tg    ][2] = r0[1]; pb[2 * tg    ][3] = r1[1];
                pb[2 * tg + 1][0] = r2[0]; pb[2 * tg + 1][1] = r3[0];
                pb[2 * tg + 1][2] = r2[1]; pb[2 * tg + 1][3] = r3[1];
            }
            // ---- L3: broadcast-A MFMA chain; only row-0 reg is consumed ----
            acc[0] = b3v;
            #pragma unroll
            for (int s = 0; s < 4; ++s) {
                Frag fb;
                #pragma unroll
                for (int c = 0; c < 4; ++c) fb.u[c] = pb[s][c];
                acc = __builtin_amdgcn_mfma_f32_32x32x16_bf16(a3[s], fb.b, acc, 0, 0, 0);
            }
            res[e] = acc[0];
        }
        // two coalesced 64-wide stores per iteration
        const size_t base = (size_t)m * N + eb * 256 + it * 128;
        out[base + lane]      = half ? res[1] : res[0];
        out[base + 64 + lane] = half ? res[3] : res[2];
    }
}

// ---------------------------------------------------------------------------
// rho epilogue: block = 64 events, k = lane.
// ---------------------------------------------------------------------------
__global__ __launch_bounds__(256, 8) void rho_kernel(
    const float* __restrict__ Parameters,
    const float* __restrict__ PScal,
    const float* __restrict__ out,
    float* __restrict__ rho, int N)
{
    __shared__ float o[64][22];
    const int tid = threadIdx.x;
    const int nb  = blockIdx.x * 64;

    for (int i = tid; i < 20 * 64; i += 256) {
        const int mm = i >> 6, ev = i & 63;
        o[ev][mm] = out[(size_t)mm * N + nb + ev];
    }

    const int lane = tid & 63;
    const int wave = tid >> 6;
    const float pk1 = Parameters[lane * 5 + 0] / PScal[0];
    const float pk2 = Parameters[lane * 5 + 1] / PScal[1];
    const float pk3 = Parameters[lane * 5 + 2] / PScal[2];
    const float pk4 = Parameters[lane * 5 + 3] / PScal[3];
    const float pk5 = Parameters[lane * 5 + 4] / PScal[4];

    __syncthreads();

    #pragma unroll 4
    for (int i = 0; i < 16; ++i) {
        const int ev = wave * 16 + i;
        const float* r = &o[ev][0];
        float m0 = 1.0f + r[0] * pk1 + r[1] * pk2 + r[2] * pk3 + r[3] * pk4 + r[4] * pk5;
        float m1 = r[5] * pk1 + r[6] * pk2 + r[7] * pk3 + r[8] * pk4 + r[9] * pk5;
        float m2 = r[10] * pk2 + r[11] * pk3 + r[12] * pk4 + r[13] * pk5;
        float m3 = r[14] * pk3 + r[15] * pk4 + r[16] * pk5;
        float m4 = r[17] * pk4 + r[18] * pk5;
        float m5 = r[19] * pk5;
        float v = m0 * m0 + m1 * m1 + m2 * m2 + m3 * m3 + m4 * m4 + m5 * m5;
        rho[(size_t)(nb + ev) * 64 + lane] = v;
    }
}

extern "C" void kernel_launch(void* const* d_in, const int* in_sizes, int n_in,
                              void* d_out, int out_size, void* d_ws, size_t ws_size,
                              hipStream_t stream)
{
    const float* Data   = (const float*)d_in[0];
    const float* Params = (const float*)d_in[1];
    const float* Shift  = (const float*)d_in[2];
    const float* Scal   = (const float*)d_in[3];
    const float* PScal  = (const float*)d_in[4];
    const float* W1     = (const float*)d_in[5];
    const float* b1     = (const float*)d_in[6];
    const float* W2     = (const float*)d_in[7];
    const float* b2     = (const float*)d_in[8];
    const float* W3     = (const float*)d_in[9];
    const float* b3     = (const float*)d_in[10];
    float* rho = (float*)d_out;
    const int N = in_sizes[0] / 16;   // 131072

    char* ws = (char*)d_ws;
    unsigned short* w1bf = (unsigned short*)(ws);             //      0 .. 40960
    unsigned short* w2f  = (unsigned short*)(ws + 40960);     //  40960 .. 204800
    unsigned short* w3b  = (unsigned short*)(ws + 204800);    // 204800 .. 207360
    unsigned*       b1p  = (unsigned*)(ws + 207360);          // 207360 .. 209920
    unsigned*       b2p  = (unsigned*)(ws + 209920);          // 209920 .. 212480
    unsigned short* xfb  = (unsigned short*)(ws + 262144);    // 4 MB
    float*          out  = (float*)(ws + 262144 + 4194304);   // 10.5 MB ([20][N])

    prep_kernel<<<320 + N / 128, 256, 0, stream>>>(W1, W2, b1, b2, W3,
                                                   Data, Shift, Scal,
                                                   w1bf, w2f, w3b, b1p, b2p, xfb);
    mlp_kernel<<<5 * (N / 256), 256, 0, stream>>>(w1bf, w2f, w3b, b1p, b2p, b3, xfb, out, N);
    rho_kernel<<<N / 64, 256, 0, stream>>>(Params, PScal, out, rho, N);
}

// Round 11
// 61.837 us; speedup vs baseline: 2.8921x; 1.7855x over previous
//
#include <hip/hip_runtime.h>

typedef float    f32x4  __attribute__((ext_vector_type(4)));
typedef float    f32x16 __attribute__((ext_vector_type(16)));
typedef __bf16   bf16x8 __attribute__((ext_vector_type(8)));
typedef __bf16   bf16x2 __attribute__((ext_vector_type(2)));
typedef unsigned uint2v __attribute__((ext_vector_type(2)));
typedef unsigned u32x4  __attribute__((ext_vector_type(4)));

union Frag { unsigned u[4]; bf16x8 b; };

static __device__ __forceinline__ unsigned pack2(float a, float b) {
    bf16x2 t;
    t[0] = (__bf16)a;
    t[1] = (__bf16)b;
    return __builtin_bit_cast(unsigned, t);
}

// packed relu on 2xbf16: bf16 bit patterns reinterpret as f16 with monotone
// ordering for the magnitudes reachable here, so v_pk_max_f16 with +0 is an
// exact bf16 relu. 2 instr/dword vs 3 (2 fmax + cvt_pk).
static __device__ __forceinline__ unsigned relupk(float a, float b, unsigned zero) {
    unsigned x = pack2(a, b), r;
    asm("v_pk_max_f16 %0, %1, %2" : "=v"(r) : "v"(x), "v"(zero));
    return r;
}

static __device__ __forceinline__ unsigned short f2bfu(float x) {
    __bf16 b = (__bf16)x;
    return __builtin_bit_cast(unsigned short, b);
}

// unpack packed-bf16 dword -> two f32 (lo element, hi element)
static __device__ __forceinline__ float bflo(unsigned u) { return __builtin_bit_cast(float, u << 16); }
static __device__ __forceinline__ float bfhi(unsigned u) { return __builtin_bit_cast(float, u & 0xffff0000u); }

static __device__ __forceinline__ uint2v pswap(unsigned a, unsigned b) {
#if __has_builtin(__builtin_amdgcn_permlane32_swap)
    return __builtin_amdgcn_permlane32_swap(a, b, false, false);
#else
    unsigned ax = (unsigned)__shfl_xor((int)a, 32);
    unsigned bx = (unsigned)__shfl_xor((int)b, 32);
    bool lo = (__lane_id() & 32) == 0;
    uint2v r;
    r[0] = lo ? a : bx;
    r[1] = lo ? ax : b;
    return r;
#endif
}

// ---------------------------------------------------------------------------
// Combined preprocess: blocks [0,320) weight scatter; blocks [320,...) x prep.
//  w1bf: [20][64][16] bf16 natural              (A-frag: lane 16B = 8 d)
//  w2f : [20][f][64][8] bf16, f=tg*4+kk, value = W2[m][32(f>>2)+(l&31)][16(f&3)+8(l>>5)+j]
//  w3b : [20][64] bf16 natural                  (broadcast A-frags for L3 MFMA)
//  b1p/b2p: [20][t][half][8] packed bf16 pairs in C-frag order:
//           dword q = pack(b[h0], b[h0+1]),  h0 = 32t + 4*half + (2q&3) + 8*(2q>>2)
//  xfbuf[((t32*2+half)*32+ln)*8 + j] = x[32*t32+ln][8*half+j]  (N*2 threads)
// ---------------------------------------------------------------------------
__global__ __launch_bounds__(256, 4) void prep_kernel(
    const float* __restrict__ W1, const float* __restrict__ W2,
    const float* __restrict__ b1, const float* __restrict__ b2,
    const float* __restrict__ W3,
    const float* __restrict__ Data,
    const float* __restrict__ Shift,
    const float* __restrict__ Scaling,
    unsigned short* __restrict__ w1bf, unsigned short* __restrict__ w2f,
    unsigned short* __restrict__ w3b,
    unsigned* __restrict__ b1p, unsigned* __restrict__ b2p,
    unsigned short* __restrict__ xfbuf)
{
    if (blockIdx.x < 320) {
        const int t = blockIdx.x * 256 + threadIdx.x;
        if (t < 20480) w1bf[t] = f2bfu(W1[t]);
        if (t < 81920) {
            const int j = t & 7, l = (t >> 3) & 63, f = (t >> 9) & 7, m = t >> 12;
            const int g = 32 * (f >> 2) + (l & 31);
            const int h = 16 * (f & 3) + 8 * (l >> 5) + j;
            w2f[t] = f2bfu(W2[(m * 64 + g) * 64 + h]);
        }
        if (t < 1280) w3b[t] = f2bfu(W3[t]);
        if (t < 640) {
            const int q = t & 7, hf = (t >> 3) & 1, tt = (t >> 4) & 1, m = t >> 5;
            const int h0 = 32 * tt + 4 * hf + ((2 * q) & 3) + 8 * ((2 * q) >> 2);
            b1p[t] = pack2(b1[m * 64 + h0], b1[m * 64 + h0 + 1]);
            b2p[t] = pack2(b2[m * 64 + h0], b2[m * 64 + h0 + 1]);
        }
    } else {
        const int g    = (blockIdx.x - 320) * 256 + threadIdx.x;
        const int ln   = g & 31, half = (g >> 5) & 1, t32 = g >> 6;
        const float* dp = Data + (size_t)(t32 * 32 + ln) * 16 + 8 * half;
        f32x4 v0 = *(const f32x4*)dp;
        f32x4 v1 = *(const f32x4*)(dp + 4);
        float xv[8];
        #pragma unroll
        for (int j = 0; j < 4; ++j) {
            xv[j]     = (v0[j] - Shift[8 * half + j])     / Scaling[8 * half + j];
            xv[4 + j] = (v1[j] - Shift[8 * half + 4 + j]) / Scaling[8 * half + 4 + j];
        }
        u32x4 o;
        #pragma unroll
        for (int c = 0; c < 4; ++c) o[c] = pack2(xv[2 * c], xv[2 * c + 1]);
        *(u32x4*)(xfbuf + (size_t)g * 8) = o;
    }
}

// ---------------------------------------------------------------------------
// MLP, weight-stationary, E=4 per iteration.
// Occupancy ladder mapped: 4 waves/SIMD -> 614 MB spill (R9); 3 waves ->
// 210-345 MB spill (R5/R10, true total footprint > 170 regs incl. unified
// AGPRs); 2 waves -> clean (R8). (256,2) is the residency ceiling for this
// structure -- the remaining lever is shortening the per-wave serial path:
//  - L3 split into two independent 2-deep MFMA chains (C-init b3v / 0),
//    removing ~100 cyc MFMA-result latency per tile.
//  - relupk (v_pk_max_f16) keeps the VALU cut from R10, now unconfounded.
// Spill tripwire: WRITE_SIZE must stay ~10.2 MB.
// ---------------------------------------------------------------------------
__global__ __launch_bounds__(256, 2) void mlp_kernel(
    const unsigned short* __restrict__ w1bf,
    const unsigned short* __restrict__ w2f,
    const unsigned short* __restrict__ w3b,
    const unsigned* __restrict__ b1p,
    const unsigned* __restrict__ b2p,
    const float* __restrict__ b3,
    const unsigned short* __restrict__ xfbuf,
    float* __restrict__ out, int N)
{
    const int tid  = threadIdx.x;
    const int wave = tid >> 6;
    const int lane = tid & 63;
    const int ln   = lane & 31;
    const int half = lane >> 5;
    const int mg   = blockIdx.x % 5;
    const int eb   = blockIdx.x / 5;          // 0..511, 256 events each
    const int m    = mg * 4 + wave;

    unsigned zero = 0;
    asm volatile("" : "+v"(zero));   // pin 0 in a VGPR for v_pk_max_f16

    // ---- load-once, register-resident ----
    bf16x8 a1[2];
    #pragma unroll
    for (int t = 0; t < 2; ++t)
        a1[t] = *(const bf16x8*)(w1bf + (size_t)(m * 64 + 32 * t + ln) * 16 + 8 * half);
    bf16x8 a2[8];
    #pragma unroll
    for (int f = 0; f < 8; ++f)
        a2[f] = *(const bf16x8*)(w2f + (size_t)((m * 8 + f) * 64 + lane) * 8);
    bf16x8 a3[4];   // w3 broadcast slices: every A row = w3[16s + 8half + j]
    #pragma unroll
    for (int s = 0; s < 4; ++s)
        a3[s] = *(const bf16x8*)(w3b + m * 64 + s * 16 + 8 * half);
    const float b3v = b3[m];

    // packed biases (16 dwords persistent; unpack per use)
    u32x4 b1r[2][2], b2r[2][2];
    #pragma unroll
    for (int t = 0; t < 2; ++t) {
        const unsigned* p1 = b1p + ((m * 2 + t) * 2 + half) * 8;
        b1r[t][0] = *(const u32x4*)p1;
        b1r[t][1] = *(const u32x4*)(p1 + 4);
        const unsigned* p2 = b2p + ((m * 2 + t) * 2 + half) * 8;
        b2r[t][0] = *(const u32x4*)p2;
        b2r[t][1] = *(const u32x4*)(p2 + 4);
    }

    // all 8 x-fragments for this wave's 256 events (32 regs)
    bf16x8 xf[8];
    #pragma unroll
    for (int f = 0; f < 8; ++f)
        xf[f] = *(const bf16x8*)(xfbuf + ((size_t)(eb * 8 + f) * 2 + half) * 256 + ln * 8);

    #pragma unroll
    for (int it = 0; it < 2; ++it) {
        float res[4];
        #pragma unroll
        for (int e = 0; e < 4; ++e) {
            const bf16x8 xfe = xf[it * 4 + e];
            // ---- L1 ----
            unsigned bfr[4][4];
            #pragma unroll
            for (int t = 0; t < 2; ++t) {
                f32x16 acc;
                #pragma unroll
                for (int hq = 0; hq < 2; ++hq)
                    #pragma unroll
                    for (int q4 = 0; q4 < 4; ++q4) {
                        const unsigned u = b1r[t][hq][q4];
                        acc[8 * hq + 2 * q4]     = bflo(u);
                        acc[8 * hq + 2 * q4 + 1] = bfhi(u);
                    }
                acc = __builtin_amdgcn_mfma_f32_32x32x16_bf16(a1[t], xfe, acc, 0, 0, 0);
                unsigned p[8];
                #pragma unroll
                for (int q = 0; q < 8; ++q)
                    p[q] = relupk(acc[2 * q], acc[2 * q + 1], zero);
                uint2v r0 = pswap(p[0], p[2]);
                uint2v r1 = pswap(p[1], p[3]);
                uint2v r2 = pswap(p[4], p[6]);
                uint2v r3 = pswap(p[5], p[7]);
                bfr[2 * t    ][0] = r0[0]; bfr[2 * t    ][1] = r1[0];
                bfr[2 * t    ][2] = r0[1]; bfr[2 * t    ][3] = r1[1];
                bfr[2 * t + 1][0] = r2[0]; bfr[2 * t + 1][1] = r3[0];
                bfr[2 * t + 1][2] = r2[1]; bfr[2 * t + 1][3] = r3[1];
            }
            // ---- L2: two independent tg-chains, interleaved in source ----
            Frag fb0[4], fb1[4];
            #pragma unroll
            for (int kk = 0; kk < 4; ++kk) {
                #pragma unroll
                for (int c = 0; c < 4; ++c) { fb0[kk].u[c] = bfr[kk][c]; fb1[kk].u[c] = bfr[kk][c]; }
            }
            f32x16 ac0, ac1;
            #pragma unroll
            for (int hq = 0; hq < 2; ++hq)
                #pragma unroll
                for (int q4 = 0; q4 < 4; ++q4) {
                    const unsigned u0 = b2r[0][hq][q4];
                    const unsigned u1 = b2r[1][hq][q4];
                    ac0[8 * hq + 2 * q4]     = bflo(u0);
                    ac0[8 * hq + 2 * q4 + 1] = bfhi(u0);
                    ac1[8 * hq + 2 * q4]     = bflo(u1);
                    ac1[8 * hq + 2 * q4 + 1] = bfhi(u1);
                }
            #pragma unroll
            for (int kk = 0; kk < 4; ++kk) {
                ac0 = __builtin_amdgcn_mfma_f32_32x32x16_bf16(a2[kk],     fb0[kk].b, ac0, 0, 0, 0);
                ac1 = __builtin_amdgcn_mfma_f32_32x32x16_bf16(a2[4 + kk], fb1[kk].b, ac1, 0, 0, 0);
            }
            unsigned pb[4][4];
            {
                unsigned p[8];
                #pragma unroll
                for (int q = 0; q < 8; ++q)
                    p[q] = relupk(ac0[2 * q], ac0[2 * q + 1], zero);
                uint2v r0 = pswap(p[0], p[2]);
                uint2v r1 = pswap(p[1], p[3]);
                uint2v r2 = pswap(p[4], p[6]);
                uint2v r3 = pswap(p[5], p[7]);
                pb[0][0] = r0[0]; pb[0][1] = r1[0]; pb[0][2] = r0[1]; pb[0][3] = r1[1];
                pb[1][0] = r2[0]; pb[1][1] = r3[0]; pb[1][2] = r2[1]; pb[1][3] = r3[1];
            }
            {
                unsigned p[8];
                #pragma unroll
                for (int q = 0; q < 8; ++q)
                    p[q] = relupk(ac1[2 * q], ac1[2 * q + 1], zero);
                uint2v r0 = pswap(p[0], p[2]);
                uint2v r1 = pswap(p[1], p[3]);
                uint2v r2 = pswap(p[4], p[6]);
                uint2v r3 = pswap(p[5], p[7]);
                pb[2][0] = r0[0]; pb[2][1] = r1[0]; pb[2][2] = r0[1]; pb[2][3] = r1[1];
                pb[3][0] = r2[0]; pb[3][1] = r3[0]; pb[3][2] = r2[1]; pb[3][3] = r3[1];
            }
            // ---- L3: two independent 2-deep broadcast-A MFMA chains ----
            Frag q0, q1, q2, q3;
            #pragma unroll
            for (int c = 0; c < 4; ++c) {
                q0.u[c] = pb[0][c]; q1.u[c] = pb[1][c];
                q2.u[c] = pb[2][c]; q3.u[c] = pb[3][c];
            }
            f32x16 ca = ac0; ca[0] = b3v;
            f32x16 cb = ac1; cb[0] = 0.f;
            ca = __builtin_amdgcn_mfma_f32_32x32x16_bf16(a3[0], q0.b, ca, 0, 0, 0);
            cb = __builtin_amdgcn_mfma_f32_32x32x16_bf16(a3[2], q2.b, cb, 0, 0, 0);
            ca = __builtin_amdgcn_mfma_f32_32x32x16_bf16(a3[1], q1.b, ca, 0, 0, 0);
            cb = __builtin_amdgcn_mfma_f32_32x32x16_bf16(a3[3], q3.b, cb, 0, 0, 0);
            res[e] = ca[0] + cb[0];
        }
        // two coalesced 64-wide stores per iteration
        const size_t base = (size_t)m * N + eb * 256 + it * 128;
        out[base + lane]      = half ? res[1] : res[0];
        out[base + 64 + lane] = half ? res[3] : res[2];
    }
}

// ---------------------------------------------------------------------------
// rho epilogue: block = 64 events, k = lane.
// ---------------------------------------------------------------------------
__global__ __launch_bounds__(256, 8) void rho_kernel(
    const float* __restrict__ Parameters,
    const float* __restrict__ PScal,
    const float* __restrict__ out,
    float* __restrict__ rho, int N)
{
    __shared__ float o[64][22];
    const int tid = threadIdx.x;
    const int nb  = blockIdx.x * 64;

    for (int i = tid; i < 20 * 64; i += 256) {
        const int mm = i >> 6, ev = i & 63;
        o[ev][mm] = out[(size_t)mm * N + nb + ev];
    }

    const int lane = tid & 63;
    const int wave = tid >> 6;
    const float pk1 = Parameters[lane * 5 + 0] / PScal[0];
    const float pk2 = Parameters[lane * 5 + 1] / PScal[1];
    const float pk3 = Parameters[lane * 5 + 2] / PScal[2];
    const float pk4 = Parameters[lane * 5 + 3] / PScal[3];
    const float pk5 = Parameters[lane * 5 + 4] / PScal[4];

    __syncthreads();

    #pragma unroll 4
    for (int i = 0; i < 16; ++i) {
        const int ev = wave * 16 + i;
        const float* r = &o[ev][0];
        float m0 = 1.0f + r[0] * pk1 + r[1] * pk2 + r[2] * pk3 + r[3] * pk4 + r[4] * pk5;
        float m1 = r[5] * pk1 + r[6] * pk2 + r[7] * pk3 + r[8] * pk4 + r[9] * pk5;
        float m2 = r[10] * pk2 + r[11] * pk3 + r[12] * pk4 + r[13] * pk5;
        float m3 = r[14] * pk3 + r[15] * pk4 + r[16] * pk5;
        float m4 = r[17] * pk4 + r[18] * pk5;
        float m5 = r[19] * pk5;
        float v = m0 * m0 + m1 * m1 + m2 * m2 + m3 * m3 + m4 * m4 + m5 * m5;
        rho[(size_t)(nb + ev) * 64 + lane] = v;
    }
}

extern "C" void kernel_launch(void* const* d_in, const int* in_sizes, int n_in,
                              void* d_out, int out_size, void* d_ws, size_t ws_size,
                              hipStream_t stream)
{
    const float* Data   = (const float*)d_in[0];
    const float* Params = (const float*)d_in[1];
    const float* Shift  = (const float*)d_in[2];
    const float* Scal   = (const float*)d_in[3];
    const float* PScal  = (const float*)d_in[4];
    const float* W1     = (const float*)d_in[5];
    const float* b1     = (const float*)d_in[6];
    const float* W2     = (const float*)d_in[7];
    const float* b2     = (const float*)d_in[8];
    const float* W3     = (const float*)d_in[9];
    const float* b3     = (const float*)d_in[10];
    float* rho = (float*)d_out;
    const int N = in_sizes[0] / 16;   // 131072

    char* ws = (char*)d_ws;
    unsigned short* w1bf = (unsigned short*)(ws);             //      0 .. 40960
    unsigned short* w2f  = (unsigned short*)(ws + 40960);     //  40960 .. 204800
    unsigned short* w3b  = (unsigned short*)(ws + 204800);    // 204800 .. 207360
    unsigned*       b1p  = (unsigned*)(ws + 207360);          // 207360 .. 209920
    unsigned*       b2p  = (unsigned*)(ws + 209920);          // 209920 .. 212480
    unsigned short* xfb  = (unsigned short*)(ws + 262144);    // 4 MB
    float*          out  = (float*)(ws + 262144 + 4194304);   // 10.5 MB ([20][N])

    prep_kernel<<<320 + N / 128, 256, 0, stream>>>(W1, W2, b1, b2, W3,
                                                   Data, Shift, Scal,
                                                   w1bf, w2f, w3b, b1p, b2p, xfb);
    mlp_kernel<<<5 * (N / 256), 256, 0, stream>>>(w1bf, w2f, w3b, b1p, b2p, b3, xfb, out, N);
    rho_kernel<<<N / 64, 256, 0, stream>>>(Params, PScal, out, rho, N);
}

// Round 13
// 61.270 us; speedup vs baseline: 2.9189x; 1.0092x over previous
//
#include <hip/hip_runtime.h>

typedef float    f32x4  __attribute__((ext_vector_type(4)));
typedef float    f32x16 __attribute__((ext_vector_type(16)));
typedef __bf16   bf16x8 __attribute__((ext_vector_type(8)));
typedef __bf16   bf16x2 __attribute__((ext_vector_type(2)));
typedef unsigned uint2v __attribute__((ext_vector_type(2)));
typedef unsigned u32x4  __attribute__((ext_vector_type(4)));

union Frag { unsigned u[4]; bf16x8 b; };

static __device__ __forceinline__ unsigned pack2(float a, float b) {
    bf16x2 t;
    t[0] = (__bf16)a;
    t[1] = (__bf16)b;
    return __builtin_bit_cast(unsigned, t);
}

// packed relu on 2xbf16 via v_pk_max_f16 (exact for reachable magnitudes)
static __device__ __forceinline__ unsigned relupk(float a, float b, unsigned zero) {
    unsigned x = pack2(a, b), r;
    asm("v_pk_max_f16 %0, %1, %2" : "=v"(r) : "v"(x), "v"(zero));
    return r;
}

static __device__ __forceinline__ unsigned short f2bfu(float x) {
    __bf16 b = (__bf16)x;
    return __builtin_bit_cast(unsigned short, b);
}

// unpack packed-bf16 dword -> two f32 (lo element, hi element)
static __device__ __forceinline__ float bflo(unsigned u) { return __builtin_bit_cast(float, u << 16); }
static __device__ __forceinline__ float bfhi(unsigned u) { return __builtin_bit_cast(float, u & 0xffff0000u); }

// VERIFIED convention (derived from the working L1 relayout, R1-R11):
//   pswap(a,b) -> r[0] = {low: a_low, high: b_low}
//                 r[1] = {low: a_high, high: b_high}
static __device__ __forceinline__ uint2v pswap(unsigned a, unsigned b) {
#if __has_builtin(__builtin_amdgcn_permlane32_swap)
    return __builtin_amdgcn_permlane32_swap(a, b, false, false);
#else
    unsigned ax = (unsigned)__shfl_xor((int)a, 32);
    unsigned bx = (unsigned)__shfl_xor((int)b, 32);
    bool lo = (__lane_id() & 32) == 0;
    uint2v r;
    r[0] = lo ? a : bx;
    r[1] = lo ? ax : b;
    return r;
#endif
}

// cross-half sum: s + s[lane^32]. With pswap(s,s): r[0]=(s_lo,s_lo),
// r[1]=(s_hi,s_hi). half=0 lane needs s[l+32]=r[1][l]; half=1 needs
// s[l-32]=r[0][l].  (R12 bug: selection was inverted -> each lane
// doubled its own partial; absmax 474.)
static __device__ __forceinline__ float xhalf_sum(float s, int half) {
    unsigned su = __builtin_bit_cast(unsigned, s);
    uint2v r = pswap(su, su);
    float other = __builtin_bit_cast(float, half ? r[0] : r[1]);
    return s + other;
}

// ---------------------------------------------------------------------------
// Combined preprocess: blocks [0,320) weight scatter; blocks [320,...) x prep.
//  w1bf: [20][64][16] bf16 natural              (A-frag: lane 16B = 8 d)
//  w2f : [20][f][64][8] bf16, f=tg*4+kk, value = W2[m][32(f>>2)+(l&31)][16(f&3)+8(l>>5)+j]
//  w3f : [20][t][half][16] f32 in C-frag order: value i = W3[m][32t+4*half+(i&3)+8*(i>>2)]
//  b1p/b2p: [20][t][half][8] packed bf16 pairs in C-frag order:
//           dword q = pack(b[h0], b[h0+1]),  h0 = 32t + 4*half + (2q&3) + 8*(2q>>2)
//  xfbuf[((t32*2+half)*32+ln)*8 + j] = x[32*t32+ln][8*half+j]  (N*2 threads)
// ---------------------------------------------------------------------------
__global__ __launch_bounds__(256, 4) void prep_kernel(
    const float* __restrict__ W1, const float* __restrict__ W2,
    const float* __restrict__ b1, const float* __restrict__ b2,
    const float* __restrict__ W3,
    const float* __restrict__ Data,
    const float* __restrict__ Shift,
    const float* __restrict__ Scaling,
    unsigned short* __restrict__ w1bf, unsigned short* __restrict__ w2f,
    float* __restrict__ w3f,
    unsigned* __restrict__ b1p, unsigned* __restrict__ b2p,
    unsigned short* __restrict__ xfbuf)
{
    if (blockIdx.x < 320) {
        const int t = blockIdx.x * 256 + threadIdx.x;
        if (t < 20480) w1bf[t] = f2bfu(W1[t]);
        if (t < 81920) {
            const int j = t & 7, l = (t >> 3) & 63, f = (t >> 9) & 7, m = t >> 12;
            const int g = 32 * (f >> 2) + (l & 31);
            const int h = 16 * (f & 3) + 8 * (l >> 5) + j;
            w2f[t] = f2bfu(W2[(m * 64 + g) * 64 + h]);
        }
        if (t < 1280) {
            const int i = t & 15, hf = (t >> 4) & 1, tt = (t >> 5) & 1, m = t >> 6;
            const int h = 32 * tt + 4 * hf + (i & 3) + 8 * (i >> 2);
            w3f[t] = W3[m * 64 + h];
        }
        if (t < 640) {
            const int q = t & 7, hf = (t >> 3) & 1, tt = (t >> 4) & 1, m = t >> 5;
            const int h0 = 32 * tt + 4 * hf + ((2 * q) & 3) + 8 * ((2 * q) >> 2);
            b1p[t] = pack2(b1[m * 64 + h0], b1[m * 64 + h0 + 1]);
            b2p[t] = pack2(b2[m * 64 + h0], b2[m * 64 + h0 + 1]);
        }
    } else {
        const int g    = (blockIdx.x - 320) * 256 + threadIdx.x;
        const int ln   = g & 31, half = (g >> 5) & 1, t32 = g >> 6;
        const float* dp = Data + (size_t)(t32 * 32 + ln) * 16 + 8 * half;
        f32x4 v0 = *(const f32x4*)dp;
        f32x4 v1 = *(const f32x4*)(dp + 4);
        float xv[8];
        #pragma unroll
        for (int j = 0; j < 4; ++j) {
            xv[j]     = (v0[j] - Shift[8 * half + j])     / Scaling[8 * half + j];
            xv[4 + j] = (v1[j] - Shift[8 * half + 4 + j]) / Scaling[8 * half + 4 + j];
        }
        u32x4 o;
        #pragma unroll
        for (int c = 0; c < 4; ++c) o[c] = pack2(xv[2 * c], xv[2 * c + 1]);
        *(u32x4*)(xfbuf + (size_t)g * 8) = o;
    }
}

// ---------------------------------------------------------------------------
// MLP, weight-stationary, E=4 per iteration, VALU L3 (fixed xhalf_sum).
// L3 on the VALU directly off the L2 accumulators (w3 pre-scattered to
// C-frag-order f32): 32 parallel fmax+fma into 4 partials + permlane
// cross-half combine. Deletes 4 MFMAs + 24 pack ops + ~300 cyc serial tail
// per e-chain; relu(h2) stays f32. (256,2) is the residency ceiling
// (R8/R9/R10 ladder). Spill tripwire: WRITE_SIZE ~10.2 MB.
// ---------------------------------------------------------------------------
__global__ __launch_bounds__(256, 2) void mlp_kernel(
    const unsigned short* __restrict__ w1bf,
    const unsigned short* __restrict__ w2f,
    const float* __restrict__ w3f,
    const unsigned* __restrict__ b1p,
    const unsigned* __restrict__ b2p,
    const float* __restrict__ b3,
    const unsigned short* __restrict__ xfbuf,
    float* __restrict__ out, int N)
{
    const int tid  = threadIdx.x;
    const int wave = tid >> 6;
    const int lane = tid & 63;
    const int ln   = lane & 31;
    const int half = lane >> 5;
    const int mg   = blockIdx.x % 5;
    const int eb   = blockIdx.x / 5;          // 0..511, 256 events each
    const int m    = mg * 4 + wave;

    unsigned zero = 0;
    asm volatile("" : "+v"(zero));   // pin 0 in a VGPR for v_pk_max_f16

    // ---- load-once, register-resident ----
    bf16x8 a1[2];
    #pragma unroll
    for (int t = 0; t < 2; ++t)
        a1[t] = *(const bf16x8*)(w1bf + (size_t)(m * 64 + 32 * t + ln) * 16 + 8 * half);
    bf16x8 a2[8];
    #pragma unroll
    for (int f = 0; f < 8; ++f)
        a2[f] = *(const bf16x8*)(w2f + (size_t)((m * 8 + f) * 64 + lane) * 8);
    f32x16 w3r[2];   // C-frag-order w3 (32 regs), matches ac element mapping
    #pragma unroll
    for (int t = 0; t < 2; ++t)
        w3r[t] = *(const f32x16*)(w3f + ((m * 2 + t) * 2 + half) * 16);
    const float b3v = b3[m];

    // packed biases (16 dwords persistent; unpack per use)
    u32x4 b1r[2][2], b2r[2][2];
    #pragma unroll
    for (int t = 0; t < 2; ++t) {
        const unsigned* p1 = b1p + ((m * 2 + t) * 2 + half) * 8;
        b1r[t][0] = *(const u32x4*)p1;
        b1r[t][1] = *(const u32x4*)(p1 + 4);
        const unsigned* p2 = b2p + ((m * 2 + t) * 2 + half) * 8;
        b2r[t][0] = *(const u32x4*)p2;
        b2r[t][1] = *(const u32x4*)(p2 + 4);
    }

    // all 8 x-fragments for this wave's 256 events (32 regs)
    bf16x8 xf[8];
    #pragma unroll
    for (int f = 0; f < 8; ++f)
        xf[f] = *(const bf16x8*)(xfbuf + ((size_t)(eb * 8 + f) * 2 + half) * 256 + ln * 8);

    #pragma unroll
    for (int it = 0; it < 2; ++it) {
        float res[4];
        #pragma unroll
        for (int e = 0; e < 4; ++e) {
            const bf16x8 xfe = xf[it * 4 + e];
            // ---- L1 ----
            unsigned bfr[4][4];
            #pragma unroll
            for (int t = 0; t < 2; ++t) {
                f32x16 acc;
                #pragma unroll
                for (int hq = 0; hq < 2; ++hq)
                    #pragma unroll
                    for (int q4 = 0; q4 < 4; ++q4) {
                        const unsigned u = b1r[t][hq][q4];
                        acc[8 * hq + 2 * q4]     = bflo(u);
                        acc[8 * hq + 2 * q4 + 1] = bfhi(u);
                    }
                acc = __builtin_amdgcn_mfma_f32_32x32x16_bf16(a1[t], xfe, acc, 0, 0, 0);
                unsigned p[8];
                #pragma unroll
                for (int q = 0; q < 8; ++q)
                    p[q] = relupk(acc[2 * q], acc[2 * q + 1], zero);
                uint2v r0 = pswap(p[0], p[2]);
                uint2v r1 = pswap(p[1], p[3]);
                uint2v r2 = pswap(p[4], p[6]);
                uint2v r3 = pswap(p[5], p[7]);
                bfr[2 * t    ][0] = r0[0]; bfr[2 * t    ][1] = r1[0];
                bfr[2 * t    ][2] = r0[1]; bfr[2 * t    ][3] = r1[1];
                bfr[2 * t + 1][0] = r2[0]; bfr[2 * t + 1][1] = r3[0];
                bfr[2 * t + 1][2] = r2[1]; bfr[2 * t + 1][3] = r3[1];
            }
            // ---- L2: two independent tg-chains, interleaved in source ----
            Frag fb[4];
            #pragma unroll
            for (int kk = 0; kk < 4; ++kk)
                #pragma unroll
                for (int c = 0; c < 4; ++c) fb[kk].u[c] = bfr[kk][c];
            f32x16 ac0, ac1;
            #pragma unroll
            for (int hq = 0; hq < 2; ++hq)
                #pragma unroll
                for (int q4 = 0; q4 < 4; ++q4) {
                    const unsigned u0 = b2r[0][hq][q4];
                    const unsigned u1 = b2r[1][hq][q4];
                    ac0[8 * hq + 2 * q4]     = bflo(u0);
                    ac0[8 * hq + 2 * q4 + 1] = bfhi(u0);
                    ac1[8 * hq + 2 * q4]     = bflo(u1);
                    ac1[8 * hq + 2 * q4 + 1] = bfhi(u1);
                }
            #pragma unroll
            for (int kk = 0; kk < 4; ++kk) {
                ac0 = __builtin_amdgcn_mfma_f32_32x32x16_bf16(a2[kk],     fb[kk].b, ac0, 0, 0, 0);
                ac1 = __builtin_amdgcn_mfma_f32_32x32x16_bf16(a2[4 + kk], fb[kk].b, ac1, 0, 0, 0);
            }
            // ---- L3 on VALU: 32 parallel fmax+fma, 4 partials, depth 8 ----
            float s0 = 0.f, s1 = 0.f, s2 = 0.f, s3 = 0.f;
            #pragma unroll
            for (int q = 0; q < 4; ++q) {
                s0 = fmaf(w3r[0][4 * q + 0], fmaxf(ac0[4 * q + 0], 0.f), s0);
                s1 = fmaf(w3r[0][4 * q + 1], fmaxf(ac0[4 * q + 1], 0.f), s1);
                s2 = fmaf(w3r[0][4 * q + 2], fmaxf(ac0[4 * q + 2], 0.f), s2);
                s3 = fmaf(w3r[0][4 * q + 3], fmaxf(ac0[4 * q + 3], 0.f), s3);
                s0 = fmaf(w3r[1][4 * q + 0], fmaxf(ac1[4 * q + 0], 0.f), s0);
                s1 = fmaf(w3r[1][4 * q + 1], fmaxf(ac1[4 * q + 1], 0.f), s1);
                s2 = fmaf(w3r[1][4 * q + 2], fmaxf(ac1[4 * q + 2], 0.f), s2);
                s3 = fmaf(w3r[1][4 * q + 3], fmaxf(ac1[4 * q + 3], 0.f), s3);
            }
            const float s = (s0 + s1) + (s2 + s3);
            res[e] = xhalf_sum(s, half) + b3v;
        }
        // two coalesced 64-wide stores per iteration
        const size_t base = (size_t)m * N + eb * 256 + it * 128;
        out[base + lane]      = half ? res[1] : res[0];
        out[base + 64 + lane] = half ? res[3] : res[2];
    }
}

// ---------------------------------------------------------------------------
// rho epilogue: block = 64 events, k = lane.
// ---------------------------------------------------------------------------
__global__ __launch_bounds__(256, 8) void rho_kernel(
    const float* __restrict__ Parameters,
    const float* __restrict__ PScal,
    const float* __restrict__ out,
    float* __restrict__ rho, int N)
{
    __shared__ float o[64][22];
    const int tid = threadIdx.x;
    const int nb  = blockIdx.x * 64;

    for (int i = tid; i < 20 * 64; i += 256) {
        const int mm = i >> 6, ev = i & 63;
        o[ev][mm] = out[(size_t)mm * N + nb + ev];
    }

    const int lane = tid & 63;
    const int wave = tid >> 6;
    const float pk1 = Parameters[lane * 5 + 0] / PScal[0];
    const float pk2 = Parameters[lane * 5 + 1] / PScal[1];
    const float pk3 = Parameters[lane * 5 + 2] / PScal[2];
    const float pk4 = Parameters[lane * 5 + 3] / PScal[3];
    const float pk5 = Parameters[lane * 5 + 4] / PScal[4];

    __syncthreads();

    #pragma unroll 4
    for (int i = 0; i < 16; ++i) {
        const int ev = wave * 16 + i;
        const float* r = &o[ev][0];
        float m0 = 1.0f + r[0] * pk1 + r[1] * pk2 + r[2] * pk3 + r[3] * pk4 + r[4] * pk5;
        float m1 = r[5] * pk1 + r[6] * pk2 + r[7] * pk3 + r[8] * pk4 + r[9] * pk5;
        float m2 = r[10] * pk2 + r[11] * pk3 + r[12] * pk4 + r[13] * pk5;
        float m3 = r[14] * pk3 + r[15] * pk4 + r[16] * pk5;
        float m4 = r[17] * pk4 + r[18] * pk5;
        float m5 = r[19] * pk5;
        float v = m0 * m0 + m1 * m1 + m2 * m2 + m3 * m3 + m4 * m4 + m5 * m5;
        rho[(size_t)(nb + ev) * 64 + lane] = v;
    }
}

extern "C" void kernel_launch(void* const* d_in, const int* in_sizes, int n_in,
                              void* d_out, int out_size, void* d_ws, size_t ws_size,
                              hipStream_t stream)
{
    const float* Data   = (const float*)d_in[0];
    const float* Params = (const float*)d_in[1];
    const float* Shift  = (const float*)d_in[2];
    const float* Scal   = (const float*)d_in[3];
    const float* PScal  = (const float*)d_in[4];
    const float* W1     = (const float*)d_in[5];
    const float* b1     = (const float*)d_in[6];
    const float* W2     = (const float*)d_in[7];
    const float* b2     = (const float*)d_in[8];
    const float* W3     = (const float*)d_in[9];
    const float* b3     = (const float*)d_in[10];
    float* rho = (float*)d_out;
    const int N = in_sizes[0] / 16;   // 131072

    char* ws = (char*)d_ws;
    unsigned short* w1bf = (unsigned short*)(ws);             //      0 .. 40960
    unsigned short* w2f  = (unsigned short*)(ws + 40960);     //  40960 .. 204800
    unsigned*       b1p  = (unsigned*)(ws + 204800);          // 204800 .. 207360
    unsigned*       b2p  = (unsigned*)(ws + 207360);          // 207360 .. 209920
    float*          w3f  = (float*)(ws + 209920);             // 209920 .. 220160
    unsigned short* xfb  = (unsigned short*)(ws + 262144);    // 4 MB
    float*          out  = (float*)(ws + 262144 + 4194304);   // 10.5 MB ([20][N])

    prep_kernel<<<320 + N / 128, 256, 0, stream>>>(W1, W2, b1, b2, W3,
                                                   Data, Shift, Scal,
                                                   w1bf, w2f, w3f, b1p, b2p, xfb);
    mlp_kernel<<<5 * (N / 256), 256, 0, stream>>>(w1bf, w2f, w3f, b1p, b2p, b3, xfb, out, N);
    rho_kernel<<<N / 64, 256, 0, stream>>>(Params, PScal, out, rho, N);
}

// Round 14
// 57.210 us; speedup vs baseline: 3.1260x; 1.0710x over previous
//
#include <hip/hip_runtime.h>

typedef float    f32x4  __attribute__((ext_vector_type(4)));
typedef float    f32x16 __attribute__((ext_vector_type(16)));
typedef __bf16   bf16x8 __attribute__((ext_vector_type(8)));
typedef __bf16   bf16x2 __attribute__((ext_vector_type(2)));
typedef unsigned uint2v __attribute__((ext_vector_type(2)));
typedef unsigned u32x4  __attribute__((ext_vector_type(4)));

union Frag { unsigned u[4]; bf16x8 b; };

static __device__ __forceinline__ unsigned pack2(float a, float b) {
    bf16x2 t;
    t[0] = (__bf16)a;
    t[1] = (__bf16)b;
    return __builtin_bit_cast(unsigned, t);
}

// packed relu on 2xbf16 via v_pk_max_f16 (exact for reachable magnitudes)
static __device__ __forceinline__ unsigned relupk(float a, float b, unsigned zero) {
    unsigned x = pack2(a, b), r;
    asm("v_pk_max_f16 %0, %1, %2" : "=v"(r) : "v"(x), "v"(zero));
    return r;
}

static __device__ __forceinline__ unsigned short f2bfu(float x) {
    __bf16 b = (__bf16)x;
    return __builtin_bit_cast(unsigned short, b);
}

// unpack packed-bf16 dword -> two f32 (lo element, hi element)
static __device__ __forceinline__ float bflo(unsigned u) { return __builtin_bit_cast(float, u << 16); }
static __device__ __forceinline__ float bfhi(unsigned u) { return __builtin_bit_cast(float, u & 0xffff0000u); }

// VERIFIED convention (derived from the working L1 relayout, R1-R13):
//   pswap(a,b) -> r[0] = {low: a_low, high: b_low}
//                 r[1] = {low: a_high, high: b_high}
static __device__ __forceinline__ uint2v pswap(unsigned a, unsigned b) {
#if __has_builtin(__builtin_amdgcn_permlane32_swap)
    return __builtin_amdgcn_permlane32_swap(a, b, false, false);
#else
    unsigned ax = (unsigned)__shfl_xor((int)a, 32);
    unsigned bx = (unsigned)__shfl_xor((int)b, 32);
    bool lo = (__lane_id() & 32) == 0;
    uint2v r;
    r[0] = lo ? a : bx;
    r[1] = lo ? ax : b;
    return r;
#endif
}

// cross-half sum: s + s[lane^32] (R13-verified selection)
static __device__ __forceinline__ float xhalf_sum(float s, int half) {
    unsigned su = __builtin_bit_cast(unsigned, s);
    uint2v r = pswap(su, su);
    float other = __builtin_bit_cast(float, half ? r[0] : r[1]);
    return s + other;
}

// ---------------------------------------------------------------------------
// Weight preprocess only (320 blocks).
//  w1bf: [20][64][16] bf16 natural              (A-frag: lane 16B = 8 d)
//  w2f : [20][f][64][8] bf16, f=tg*4+kk, value = W2[m][32(f>>2)+(l&31)][16(f&3)+8(l>>5)+j]
//  w3f : [20][t][half][16] f32 in C-frag order: value i = W3[m][32t+4*half+(i&3)+8*(i>>2)]
//  b1p/b2p: [20][t][half][8] packed bf16 pairs in C-frag order
// ---------------------------------------------------------------------------
__global__ __launch_bounds__(256, 4) void prep_kernel(
    const float* __restrict__ W1, const float* __restrict__ W2,
    const float* __restrict__ b1, const float* __restrict__ b2,
    const float* __restrict__ W3,
    unsigned short* __restrict__ w1bf, unsigned short* __restrict__ w2f,
    float* __restrict__ w3f,
    unsigned* __restrict__ b1p, unsigned* __restrict__ b2p)
{
    const int t = blockIdx.x * 256 + threadIdx.x;
    if (t < 20480) w1bf[t] = f2bfu(W1[t]);
    if (t < 81920) {
        const int j = t & 7, l = (t >> 3) & 63, f = (t >> 9) & 7, m = t >> 12;
        const int g = 32 * (f >> 2) + (l & 31);
        const int h = 16 * (f & 3) + 8 * (l >> 5) + j;
        w2f[t] = f2bfu(W2[(m * 64 + g) * 64 + h]);
    }
    if (t < 1280) {
        const int i = t & 15, hf = (t >> 4) & 1, tt = (t >> 5) & 1, m = t >> 6;
        const int h = 32 * tt + 4 * hf + (i & 3) + 8 * (i >> 2);
        w3f[t] = W3[m * 64 + h];
    }
    if (t < 640) {
        const int q = t & 7, hf = (t >> 3) & 1, tt = (t >> 4) & 1, m = t >> 5;
        const int h0 = 32 * tt + 4 * hf + ((2 * q) & 3) + 8 * ((2 * q) >> 2);
        b1p[t] = pack2(b1[m * 64 + h0], b1[m * 64 + h0 + 1]);
        b2p[t] = pack2(b2[m * 64 + h0], b2[m * 64 + h0 + 1]);
    }
}

// ---------------------------------------------------------------------------
// Fully fused: block = 256 events x ALL 20 networks (4 waves x 5 m each,
// weights reloaded per m from L2-resident staging) + in-block rho epilogue.
// R13 post-mortem: mlp pinned ~43us by schedule; the lever is the ~18us of
// non-mlp time (xprep dispatch, out 21MB round-trip, rho launch). Fused:
// x-fragments computed inline from Data; MLP outputs -> LDS o[256][24]
// (stride 24: 16B-aligned rows for b128 broadcast reads); one barrier; rho
// tail with k=lane, coalesced 256B stores. (256,2) residency ceiling per
// R8/R9/R10 ladder. Spill tripwire: WRITE_SIZE ~33.5 MB (rho only).
// ---------------------------------------------------------------------------
__global__ __launch_bounds__(256, 2) void fused_kernel(
    const unsigned short* __restrict__ w1bf,
    const unsigned short* __restrict__ w2f,
    const float* __restrict__ w3f,
    const unsigned* __restrict__ b1p,
    const unsigned* __restrict__ b2p,
    const float* __restrict__ b3,
    const float* __restrict__ Data,
    const float* __restrict__ Shift,
    const float* __restrict__ Scaling,
    const float* __restrict__ Parameters,
    const float* __restrict__ PScal,
    float* __restrict__ rho, int N)
{
    __shared__ float o[256][24];   // [event][network]; stride 24 floats = 96B (16B-aligned rows)

    const int tid  = threadIdx.x;
    const int wave = tid >> 6;
    const int lane = tid & 63;
    const int ln   = lane & 31;
    const int half = lane >> 5;
    const int eb   = blockIdx.x;
    const int n0   = eb * 256;

    unsigned zero = 0;
    asm volatile("" : "+v"(zero));   // pin 0 in a VGPR for v_pk_max_f16

    // ---- inline x preprocessing: 8 bf16 B-fragments (32 regs) ----
    float sh[8], is[8];
    #pragma unroll
    for (int j = 0; j < 8; ++j) {
        sh[j] = Shift[8 * half + j];
        is[j] = 1.0f / Scaling[8 * half + j];
    }
    bf16x8 xf[8];
    #pragma unroll
    for (int f = 0; f < 8; ++f) {
        const float* dp = Data + (size_t)(n0 + 32 * f + ln) * 16 + 8 * half;
        f32x4 v0 = *(const f32x4*)dp;
        f32x4 v1 = *(const f32x4*)(dp + 4);
        float xv[8];
        #pragma unroll
        for (int j = 0; j < 4; ++j) {
            xv[j]     = (v0[j] - sh[j])     * is[j];
            xv[4 + j] = (v1[j] - sh[4 + j]) * is[4 + j];
        }
        Frag fx;
        #pragma unroll
        for (int c = 0; c < 4; ++c) fx.u[c] = pack2(xv[2 * c], xv[2 * c + 1]);
        xf[f] = fx.b;
    }

    // ---- per-lane rho coefficients (k = lane), used after the barrier ----
    const float pk1 = Parameters[lane * 5 + 0] / PScal[0];
    const float pk2 = Parameters[lane * 5 + 1] / PScal[1];
    const float pk3 = Parameters[lane * 5 + 2] / PScal[2];
    const float pk4 = Parameters[lane * 5 + 3] / PScal[3];
    const float pk5 = Parameters[lane * 5 + 4] / PScal[4];

    // ---- MLP: 5 networks per wave, weights register-resident per m ----
    for (int mi = 0; mi < 5; ++mi) {
        const int m = wave * 5 + mi;
        bf16x8 a1[2];
        #pragma unroll
        for (int t = 0; t < 2; ++t)
            a1[t] = *(const bf16x8*)(w1bf + (size_t)(m * 64 + 32 * t + ln) * 16 + 8 * half);
        bf16x8 a2[8];
        #pragma unroll
        for (int f = 0; f < 8; ++f)
            a2[f] = *(const bf16x8*)(w2f + (size_t)((m * 8 + f) * 64 + lane) * 8);
        f32x16 w3r[2];
        #pragma unroll
        for (int t = 0; t < 2; ++t)
            w3r[t] = *(const f32x16*)(w3f + ((m * 2 + t) * 2 + half) * 16);
        const float b3v = b3[m];
        u32x4 b1r[2][2], b2r[2][2];
        #pragma unroll
        for (int t = 0; t < 2; ++t) {
            const unsigned* p1 = b1p + ((m * 2 + t) * 2 + half) * 8;
            b1r[t][0] = *(const u32x4*)p1;
            b1r[t][1] = *(const u32x4*)(p1 + 4);
            const unsigned* p2 = b2p + ((m * 2 + t) * 2 + half) * 8;
            b2r[t][0] = *(const u32x4*)p2;
            b2r[t][1] = *(const u32x4*)(p2 + 4);
        }

        #pragma unroll
        for (int it = 0; it < 2; ++it) {
            float res[4];
            #pragma unroll
            for (int e = 0; e < 4; ++e) {
                const bf16x8 xfe = xf[it * 4 + e];
                // ---- L1 ----
                unsigned bfr[4][4];
                #pragma unroll
                for (int t = 0; t < 2; ++t) {
                    f32x16 acc;
                    #pragma unroll
                    for (int hq = 0; hq < 2; ++hq)
                        #pragma unroll
                        for (int q4 = 0; q4 < 4; ++q4) {
                            const unsigned u = b1r[t][hq][q4];
                            acc[8 * hq + 2 * q4]     = bflo(u);
                            acc[8 * hq + 2 * q4 + 1] = bfhi(u);
                        }
                    acc = __builtin_amdgcn_mfma_f32_32x32x16_bf16(a1[t], xfe, acc, 0, 0, 0);
                    unsigned p[8];
                    #pragma unroll
                    for (int q = 0; q < 8; ++q)
                        p[q] = relupk(acc[2 * q], acc[2 * q + 1], zero);
                    uint2v r0 = pswap(p[0], p[2]);
                    uint2v r1 = pswap(p[1], p[3]);
                    uint2v r2 = pswap(p[4], p[6]);
                    uint2v r3 = pswap(p[5], p[7]);
                    bfr[2 * t    ][0] = r0[0]; bfr[2 * t    ][1] = r1[0];
                    bfr[2 * t    ][2] = r0[1]; bfr[2 * t    ][3] = r1[1];
                    bfr[2 * t + 1][0] = r2[0]; bfr[2 * t + 1][1] = r3[0];
                    bfr[2 * t + 1][2] = r2[1]; bfr[2 * t + 1][3] = r3[1];
                }
                // ---- L2: two independent tg-chains, interleaved ----
                Frag fb[4];
                #pragma unroll
                for (int kk = 0; kk < 4; ++kk)
                    #pragma unroll
                    for (int c = 0; c < 4; ++c) fb[kk].u[c] = bfr[kk][c];
                f32x16 ac0, ac1;
                #pragma unroll
                for (int hq = 0; hq < 2; ++hq)
                    #pragma unroll
                    for (int q4 = 0; q4 < 4; ++q4) {
                        const unsigned u0 = b2r[0][hq][q4];
                        const unsigned u1 = b2r[1][hq][q4];
                        ac0[8 * hq + 2 * q4]     = bflo(u0);
                        ac0[8 * hq + 2 * q4 + 1] = bfhi(u0);
                        ac1[8 * hq + 2 * q4]     = bflo(u1);
                        ac1[8 * hq + 2 * q4 + 1] = bfhi(u1);
                    }
                #pragma unroll
                for (int kk = 0; kk < 4; ++kk) {
                    ac0 = __builtin_amdgcn_mfma_f32_32x32x16_bf16(a2[kk],     fb[kk].b, ac0, 0, 0, 0);
                    ac1 = __builtin_amdgcn_mfma_f32_32x32x16_bf16(a2[4 + kk], fb[kk].b, ac1, 0, 0, 0);
                }
                // ---- L3 on VALU ----
                float s0 = 0.f, s1 = 0.f, s2 = 0.f, s3 = 0.f;
                #pragma unroll
                for (int q = 0; q < 4; ++q) {
                    s0 = fmaf(w3r[0][4 * q + 0], fmaxf(ac0[4 * q + 0], 0.f), s0);
                    s1 = fmaf(w3r[0][4 * q + 1], fmaxf(ac0[4 * q + 1], 0.f), s1);
                    s2 = fmaf(w3r[0][4 * q + 2], fmaxf(ac0[4 * q + 2], 0.f), s2);
                    s3 = fmaf(w3r[0][4 * q + 3], fmaxf(ac0[4 * q + 3], 0.f), s3);
                    s0 = fmaf(w3r[1][4 * q + 0], fmaxf(ac1[4 * q + 0], 0.f), s0);
                    s1 = fmaf(w3r[1][4 * q + 1], fmaxf(ac1[4 * q + 1], 0.f), s1);
                    s2 = fmaf(w3r[1][4 * q + 2], fmaxf(ac1[4 * q + 2], 0.f), s2);
                    s3 = fmaf(w3r[1][4 * q + 3], fmaxf(ac1[4 * q + 3], 0.f), s3);
                }
                const float s = (s0 + s1) + (s2 + s3);
                res[e] = xhalf_sum(s, half) + b3v;
            }
            o[it * 128 + lane][m]      = half ? res[1] : res[0];
            o[it * 128 + 64 + lane][m] = half ? res[3] : res[2];
        }
    }

    __syncthreads();

    // ---- rho epilogue in-block: wave handles 64 events, k = lane ----
    #pragma unroll 4
    for (int i = 0; i < 64; ++i) {
        const int ev = wave * 64 + i;
        const f32x4* rr = (const f32x4*)&o[ev][0];   // 16B-aligned (96B rows), broadcast
        f32x4 oa = rr[0], ob = rr[1], oc = rr[2], od = rr[3], oe = rr[4];
        float m0 = 1.0f + oa[0] * pk1 + oa[1] * pk2 + oa[2] * pk3 + oa[3] * pk4 + ob[0] * pk5;
        float m1 = ob[1] * pk1 + ob[2] * pk2 + ob[3] * pk3 + oc[0] * pk4 + oc[1] * pk5;
        float m2 = oc[2] * pk2 + oc[3] * pk3 + od[0] * pk4 + od[1] * pk5;
        float m3 = od[2] * pk3 + od[3] * pk4 + oe[0] * pk5;
        float m4 = oe[1] * pk4 + oe[2] * pk5;
        float m5 = oe[3] * pk5;
        float v = m0 * m0 + m1 * m1 + m2 * m2 + m3 * m3 + m4 * m4 + m5 * m5;
        rho[(size_t)(n0 + ev) * 64 + lane] = v;
    }
}

extern "C" void kernel_launch(void* const* d_in, const int* in_sizes, int n_in,
                              void* d_out, int out_size, void* d_ws, size_t ws_size,
                              hipStream_t stream)
{
    const float* Data   = (const float*)d_in[0];
    const float* Params = (const float*)d_in[1];
    const float* Shift  = (const float*)d_in[2];
    const float* Scal   = (const float*)d_in[3];
    const float* PScal  = (const float*)d_in[4];
    const float* W1     = (const float*)d_in[5];
    const float* b1     = (const float*)d_in[6];
    const float* W2     = (const float*)d_in[7];
    const float* b2     = (const float*)d_in[8];
    const float* W3     = (const float*)d_in[9];
    const float* b3     = (const float*)d_in[10];
    float* rho = (float*)d_out;
    const int N = in_sizes[0] / 16;   // 131072

    char* ws = (char*)d_ws;
    unsigned short* w1bf = (unsigned short*)(ws);             //      0 .. 40960
    unsigned short* w2f  = (unsigned short*)(ws + 40960);     //  40960 .. 204800
    unsigned*       b1p  = (unsigned*)(ws + 204800);          // 204800 .. 207360
    unsigned*       b2p  = (unsigned*)(ws + 207360);          // 207360 .. 209920
    float*          w3f  = (float*)(ws + 209920);             // 209920 .. 220160

    prep_kernel<<<320, 256, 0, stream>>>(W1, W2, b1, b2, W3, w1bf, w2f, w3f, b1p, b2p);
    fused_kernel<<<N / 256, 256, 0, stream>>>(w1bf, w2f, w3f, b1p, b2p, b3,
                                              Data, Shift, Scal, Params, PScal, rho, N);
}